// Round 7
// baseline (106.884 us; speedup 1.0000x reference)
//
#include <hip/hip_runtime.h>
#include <math.h>

#define N 1024
#define HID 512
#define NH 16
#define DH 32
#define NEDGE 1025

typedef __attribute__((ext_vector_type(8))) __bf16 bf16x8;
typedef __attribute__((ext_vector_type(4))) short short4v;
typedef __attribute__((ext_vector_type(4))) float f32x4;

__device__ inline short f2bf(float f) {
  unsigned u = __builtin_bit_cast(unsigned, f);
  u += 0x7fffu + ((u >> 16) & 1u);
  return (short)(u >> 16);
}
__device__ inline float bf2fu(unsigned short s) {
  unsigned u = ((unsigned)s) << 16;
  return __builtin_bit_cast(float, u);
}
__device__ inline float h2f(unsigned short hs) {
  return (float)__builtin_bit_cast(_Float16, hs);
}
// OCP e4m3fn encode (RNE for normals)
__device__ inline unsigned char f2e4m3(float f) {
  unsigned u = __builtin_bit_cast(unsigned, f);
  unsigned s = (u >> 24) & 0x80;
  float a = fabsf(f);
  if (a >= 448.f) return (unsigned char)(s | 0x7e);
  if (a < 0.015625f) {                       // denormal: k × 2^-9
    int k = (int)(a * 512.f + 0.5f);
    if (k >= 8) return (unsigned char)(s | 0x08);
    return (unsigned char)(s | k);
  }
  int e = ((u >> 23) & 0xff) - 127;
  unsigned m = (u >> 20) & 7;
  unsigned rest = u & 0xfffff;
  if (rest > 0x80000 || (rest == 0x80000 && (m & 1))) {
    m += 1;
    if (m == 8) { m = 0; e += 1; if (e > 8) return (unsigned char)(s | 0x7e); }
  }
  return (unsigned char)(s | ((unsigned)(e + 7) << 3) | m);
}

// ---------------- centrality: h = x + ide[ind] + ode[outd]; also bf16 copy ---
__global__ void centrality_k(const float* __restrict__ x, const int* __restrict__ ind,
                             const int* __restrict__ outd, const float* __restrict__ ide,
                             const float* __restrict__ ode, float* __restrict__ h,
                             short* __restrict__ hb) {
  int i = blockIdx.x; int t = threadIdx.x;
  int a = ind[i], b = outd[i];
  float4 xv = ((const float4*)(x + (size_t)i*HID))[t];
  float4 av = ((const float4*)(ide + (size_t)a*HID))[t];
  float4 bv = ((const float4*)(ode + (size_t)b*HID))[t];
  float4 r;
  r.x = xv.x+av.x+bv.x; r.y = xv.y+av.y+bv.y;
  r.z = xv.z+av.z+bv.z; r.w = xv.w+av.w+bv.w;
  ((float4*)(h + (size_t)i*HID))[t] = r;
  short4v o = { f2bf(r.x), f2bf(r.y), f2bf(r.z), f2bf(r.w) };
  ((short4v*)(hb + (size_t)i*HID))[t] = o;
}

// ---------------- tables: Tb8[e][k][h]=e4m3(64*sum_d ee*pw); seb8=e4m3(se) ---
__global__ void prep_tables(const float* __restrict__ ee, const float* __restrict__ epe,
                            const float* __restrict__ se,
                            unsigned char* __restrict__ Tb8, unsigned char* __restrict__ seb8) {
  int t = blockIdx.x*256 + threadIdx.x;
  if (t < NEDGE*64) {
    int e = t >> 6; int r = t & 63; int k = r >> 4; int hh = r & 15;
    const float* erow = ee + (size_t)e*32;
    const float* w = epe + k*512 + hh;
    float acc = 0.f;
    #pragma unroll
    for (int d = 0; d < 32; ++d) acc += erow[d] * w[d*16];
    Tb8[t] = f2e4m3(acc * 64.f);
  }
  if (t < 512*16) seb8[t] = f2e4m3(se[t]);
}

// ---------------- weight transpose + bf16: Wt[n][k] = bf16(Win[k][n]) --------
__device__ inline void wtr_body(const float* __restrict__ Win, short* __restrict__ Wt,
                                int K, int Nc) {
  __shared__ float tile[32][33];
  int n0 = blockIdx.x*32, k0 = blockIdx.y*32;
  int tid = threadIdx.x;
  int r = tid >> 3, c = (tid & 7) * 4;
  float4 v = *(const float4*)(Win + (size_t)(k0+r)*Nc + n0 + c);
  tile[r][c]=v.x; tile[r][c+1]=v.y; tile[r][c+2]=v.z; tile[r][c+3]=v.w;
  __syncthreads();
  short4v o = { f2bf(tile[c+0][r]), f2bf(tile[c+1][r]), f2bf(tile[c+2][r]), f2bf(tile[c+3][r]) };
  *(short4v*)(Wt + (size_t)(n0+r)*K + k0 + c) = o;
}
__global__ void wtr_k(const float* __restrict__ Win, short* __restrict__ Wt, int K, int Nc) {
  wtr_body(Win, Wt, K, Nc);
}
__global__ void wtr4_k(const float* __restrict__ W0, const float* __restrict__ W1_,
                       const float* __restrict__ W2_, const float* __restrict__ W3,
                       short* __restrict__ T0, short* __restrict__ T1,
                       short* __restrict__ T2, short* __restrict__ T3) {
  int z = blockIdx.z;
  const float* Win = z==0 ? W0 : z==1 ? W1_ : z==2 ? W2_ : W3;
  short* Wt = z==0 ? T0 : z==1 ? T1 : z==2 ? T2 : T3;
  wtr_body(Win, Wt, 512, 512);
}

// ---------------- MFMA GEMM: C[M][Nc] = A[M][K](bf16) @ Bt[Nc][K]^T + bias ---
template<int BN, int RELU, int OUT>
__launch_bounds__(256)
__global__ void gemm_mfma(const short* __restrict__ A, const short* __restrict__ Bt,
                          const float* __restrict__ bias, float scale,
                          float* __restrict__ Cf, short* __restrict__ Cb,
                          int K, int Nc) {
  __shared__ short As[64*64];
  __shared__ short Bs[BN*64];
  constexpr int WN = BN/32;
  constexpr int WM = 4/WN;
  constexpr int MI = 64/(WM*16);
  int tid = threadIdx.x;
  int w = tid >> 6, l = tid & 63;
  int lr = l & 15, kg = l >> 4;
  int wn = (WN == 1) ? 0 : (w & 1);
  int wm = (WN == 1) ? w : (w >> 1);
  int i0 = blockIdx.y*64, n0 = blockIdx.x*BN;
  int srow = tid >> 3, sslot = tid & 7;
  f32x4 acc[MI][2];
  #pragma unroll
  for (int mi=0; mi<MI; ++mi)
    #pragma unroll
    for (int ni=0; ni<2; ++ni) acc[mi][ni] = (f32x4){0.f,0.f,0.f,0.f};
  const short* Ag = A + (size_t)i0*K;
  const short* Bg = Bt + (size_t)n0*K;
  for (int k0 = 0; k0 < K; k0 += 64) {
    bf16x8 va0 = *(const bf16x8*)(Ag + (size_t)srow*K + k0 + sslot*8);
    bf16x8 va1 = *(const bf16x8*)(Ag + (size_t)(srow+32)*K + k0 + sslot*8);
    bf16x8 vb0 = *(const bf16x8*)(Bg + (size_t)srow*K + k0 + sslot*8);
    bf16x8 vb1;
    if (BN == 64) vb1 = *(const bf16x8*)(Bg + (size_t)(srow+32)*K + k0 + sslot*8);
    __syncthreads();
    *(bf16x8*)((char*)As + srow*128 + ((sslot ^ (srow&7))<<4)) = va0;
    *(bf16x8*)((char*)As + (srow+32)*128 + ((sslot ^ (srow&7))<<4)) = va1;
    *(bf16x8*)((char*)Bs + srow*128 + ((sslot ^ (srow&7))<<4)) = vb0;
    if (BN == 64)
      *(bf16x8*)((char*)Bs + (srow+32)*128 + ((sslot ^ (srow&7))<<4)) = vb1;
    __syncthreads();
    #pragma unroll
    for (int ks = 0; ks < 2; ++ks) {
      bf16x8 fa[MI], fb[2];
      #pragma unroll
      for (int mi=0; mi<MI; ++mi) {
        int r = wm*(64/WM) + mi*16 + lr;
        fa[mi] = *(const bf16x8*)((const char*)As + r*128 + (((ks*4+kg) ^ (r&7))<<4));
      }
      #pragma unroll
      for (int ni=0; ni<2; ++ni) {
        int r = wn*32 + ni*16 + lr;
        fb[ni] = *(const bf16x8*)((const char*)Bs + r*128 + (((ks*4+kg) ^ (r&7))<<4));
      }
      #pragma unroll
      for (int mi=0; mi<MI; ++mi)
        #pragma unroll
        for (int ni=0; ni<2; ++ni)
          acc[mi][ni] = __builtin_amdgcn_mfma_f32_16x16x32_bf16(fa[mi], fb[ni], acc[mi][ni], 0, 0, 0);
    }
  }
  #pragma unroll
  for (int mi=0; mi<MI; ++mi) {
    #pragma unroll
    for (int ni=0; ni<2; ++ni) {
      int c = n0 + wn*32 + ni*16 + lr;
      float bb = bias[c];
      float vv[4];
      #pragma unroll
      for (int r=0; r<4; ++r) {
        float v = (acc[mi][ni][r] + bb) * scale;
        if (RELU) v = fmaxf(v, 0.f);
        vv[r] = v;
      }
      int rr0 = i0 + wm*(64/WM) + mi*16 + kg*4;
      if (OUT == 0) {
        #pragma unroll
        for (int r=0; r<4; ++r) Cf[(size_t)(rr0+r)*Nc + c] = vv[r];
      } else {
        #pragma unroll
        for (int r=0; r<4; ++r) Cb[(size_t)(rr0+r)*Nc + c] = f2bf(vv[r]);
      }
    }
  }
}

// ---------------- batched Q/K/V GEMM (BN=32, K=Nc=512) ----------------------
__launch_bounds__(256)
__global__ void qkv_gemm(const short* __restrict__ A,
                         const short* __restrict__ Wtq, const short* __restrict__ Wtk,
                         const short* __restrict__ Wtv,
                         const float* __restrict__ bq, const float* __restrict__ bk,
                         const float* __restrict__ bv,
                         short* __restrict__ qb, short* __restrict__ kb,
                         short* __restrict__ Vt) {
  __shared__ short As[64*64];
  __shared__ short Bs[32*64];
  int z = blockIdx.z;
  const short* Bt = z==0 ? Wtq : z==1 ? Wtk : Wtv;
  const float* bias = z==0 ? bq : z==1 ? bk : bv;
  const float scale = z==0 ? 5.65685424949238019521f : 1.f;
  int tid = threadIdx.x;
  int w = tid >> 6, l = tid & 63, lr = l & 15, kg = l >> 4;
  int i0 = blockIdx.y*64, n0 = blockIdx.x*32;
  int srow = tid >> 3, sslot = tid & 7;
  f32x4 acc[2] = {(f32x4){0,0,0,0},(f32x4){0,0,0,0}};
  const short* Ag = A + (size_t)i0*512;
  const short* Bg = Bt + (size_t)n0*512;
  for (int k0 = 0; k0 < 512; k0 += 64) {
    bf16x8 va0 = *(const bf16x8*)(Ag + (size_t)srow*512 + k0 + sslot*8);
    bf16x8 va1 = *(const bf16x8*)(Ag + (size_t)(srow+32)*512 + k0 + sslot*8);
    bf16x8 vb0 = *(const bf16x8*)(Bg + (size_t)srow*512 + k0 + sslot*8);
    __syncthreads();
    *(bf16x8*)((char*)As + srow*128 + ((sslot ^ (srow&7))<<4)) = va0;
    *(bf16x8*)((char*)As + (srow+32)*128 + ((sslot ^ (srow&7))<<4)) = va1;
    *(bf16x8*)((char*)Bs + srow*128 + ((sslot ^ (srow&7))<<4)) = vb0;
    __syncthreads();
    #pragma unroll
    for (int ks = 0; ks < 2; ++ks) {
      int ra = w*16 + lr;
      bf16x8 fa = *(const bf16x8*)((const char*)As + ra*128 + (((ks*4+kg) ^ (ra&7))<<4));
      #pragma unroll
      for (int ni=0; ni<2; ++ni) {
        int rb = ni*16 + lr;
        bf16x8 fb = *(const bf16x8*)((const char*)Bs + rb*128 + (((ks*4+kg) ^ (rb&7))<<4));
        acc[ni] = __builtin_amdgcn_mfma_f32_16x16x32_bf16(fa, fb, acc[ni], 0, 0, 0);
      }
    }
  }
  short* Cb = z==0 ? qb : kb;
  #pragma unroll
  for (int ni=0; ni<2; ++ni) {
    int c = n0 + ni*16 + lr;
    float bb = bias[c];
    float vv[4];
    #pragma unroll
    for (int r=0; r<4; ++r) vv[r] = (acc[ni][r] + bb) * scale;
    int rr0 = i0 + w*16 + kg*4;
    if (z < 2) {
      #pragma unroll
      for (int r=0; r<4; ++r) Cb[(size_t)(rr0+r)*512 + c] = f2bf(vv[r]);
    } else {
      short4v o = { f2bf(vv[0]), f2bf(vv[1]), f2bf(vv[2]), f2bf(vv[3]) };
      *(short4v*)(Vt + (size_t)c*N + rr0) = o;   // Vt[c][row]
    }
  }
}

// ---------------- bias gather: one thread per (i,j) pair ---------------------
// Bias[s][p][hp] : s = (i>>4)*16 + (j>>6), p = (i&15)*64 + (j&63), 8 f16-pairs.
__launch_bounds__(256)
__global__ void bias_gather(const int* __restrict__ sp, const int* __restrict__ ei,
                            const unsigned char* __restrict__ seb8,
                            const unsigned char* __restrict__ Tb8,
                            unsigned* __restrict__ Bias) {
  int b = blockIdx.x;                 // 0..4095
  int tid = threadIdx.x;
  int s = b >> 2, quarter = b & 3;
  int ii = quarter*4 + (tid >> 6);
  int jj = tid & 63;
  int i = (s >> 4)*16 + ii;
  int j = (s & 15)*64 + jj;
  size_t pidx = (size_t)i*N + j;
  int4 e = ((const int4*)ei)[pidx];
  int spv = sp[pidx];
  int cnt = (e.x!=0)+(e.y!=0)+(e.z!=0)+(e.w!=0);
  float inv64 = 0.015625f/(float)(cnt>0?cnt:1);
  int4 r0 = *(const int4*)(Tb8 + (size_t)e.x*64);
  int4 r1 = *(const int4*)(Tb8 + (size_t)e.y*64 + 16);
  int4 r2 = *(const int4*)(Tb8 + (size_t)e.z*64 + 32);
  int4 r3 = *(const int4*)(Tb8 + (size_t)e.w*64 + 48);
  int4 sv = *(const int4*)(seb8 + (size_t)spv*16);
  int rq[4]  = { r0.x, r0.y, r0.z, r0.w };
  int r1q[4] = { r1.x, r1.y, r1.z, r1.w };
  int r2q[4] = { r2.x, r2.y, r2.z, r2.w };
  int r3q[4] = { r3.x, r3.y, r3.z, r3.w };
  int svq[4] = { sv.x, sv.y, sv.z, sv.w };
  unsigned outw[8];
  #pragma unroll
  for (int q = 0; q < 4; ++q) {
    #define BIAS_WS(WS)                                                        \
    {                                                                          \
      auto a0 = __builtin_amdgcn_cvt_pk_f32_fp8(rq[q],  WS);                   \
      auto a1 = __builtin_amdgcn_cvt_pk_f32_fp8(r1q[q], WS);                   \
      auto a2 = __builtin_amdgcn_cvt_pk_f32_fp8(r2q[q], WS);                   \
      auto a3 = __builtin_amdgcn_cvt_pk_f32_fp8(r3q[q], WS);                   \
      auto ss = __builtin_amdgcn_cvt_pk_f32_fp8(svq[q], WS);                   \
      float tx = (a0[0]+a1[0]) + (a2[0]+a3[0]);                                \
      float ty = (a0[1]+a1[1]) + (a2[1]+a3[1]);                                \
      float bx = fmaf(tx, inv64, ss[0]);                                       \
      float by = fmaf(ty, inv64, ss[1]);                                       \
      auto pk = __builtin_amdgcn_cvt_pkrtz(bx, by);                            \
      outw[q*2+WS] = __builtin_bit_cast(unsigned, pk);                         \
    }
    BIAS_WS(0)
    BIAS_WS(1)
    #undef BIAS_WS
  }
  int4* dst = (int4*)(Bias + ((size_t)b*256 + tid)*8);
  dst[0] = make_int4((int)outw[0], (int)outw[1], (int)outw[2], (int)outw[3]);
  dst[1] = make_int4((int)outw[4], (int)outw[5], (int)outw[6], (int)outw[7]);
}

// ---------------- fused flash attention (bias pre-gathered) ------------------
// grid (16 j-chunks of 64, 64 i-tiles), 512 threads; wave w = heads 2w,2w+1.
__launch_bounds__(512, 6)
__global__ void fused_attn(const short* __restrict__ qb, const short* __restrict__ kb,
                           const short* __restrict__ Vt,
                           const unsigned* __restrict__ Bias,
                           float* __restrict__ Pm, float* __restrict__ Pl,
                           short* __restrict__ Po) {
  __shared__ unsigned bias_lds[8*1040];   // [hp][ii(16)][jj(65 pad)] f16 pairs
  int tid = threadIdx.x;
  int w = tid >> 6, l = tid & 63, lr = l & 15, kg = l >> 4;
  int i0 = blockIdx.y*16;
  int jc = blockIdx.x;
  int j0 = jc*64;
  bf16x8 qf[2];
  #pragma unroll
  for (int hh=0; hh<2; ++hh)
    qf[hh] = *(const bf16x8*)(qb + (size_t)(i0+lr)*HID + (w*2+hh)*DH + kg*8);

  // ---- phase A: coalesced slab copy global -> LDS (transposing to [hp][ii][jj])
  {
    const unsigned* slab = Bias + (size_t)(blockIdx.y*16 + jc)*8192;
    #pragma unroll
    for (int pp=0; pp<2; ++pp) {
      int p = tid*2 + pp;
      int ii = p >> 6, jj = p & 63;
      int4 a  = ((const int4*)(slab + (size_t)p*8))[0];
      int4 bb = ((const int4*)(slab + (size_t)p*8))[1];
      unsigned w8[8] = { (unsigned)a.x,(unsigned)a.y,(unsigned)a.z,(unsigned)a.w,
                         (unsigned)bb.x,(unsigned)bb.y,(unsigned)bb.z,(unsigned)bb.w };
      #pragma unroll
      for (int hp=0; hp<8; ++hp)
        bias_lds[hp*1040 + ii*65 + jj] = w8[hp];
    }
  }
  __syncthreads();

  // ---- phase B: per-wave, 2 heads ----
  float m[2], lsum[2];
  f32x4 accO[2][2];
  #pragma unroll
  for (int hh=0; hh<2; ++hh) {
    int h = w*2 + hh;
    bf16x8 kf[4];
    #pragma unroll
    for (int mi=0; mi<4; ++mi)
      kf[mi] = *(const bf16x8*)(kb + (size_t)(j0+mi*16+lr)*HID + h*DH + kg*8);
    f32x4 s[4];
    #pragma unroll
    for (int mi=0; mi<4; ++mi)
      s[mi] = __builtin_amdgcn_mfma_f32_16x16x32_bf16(kf[mi], qf[hh], (f32x4){0,0,0,0}, 0, 0, 0);
    float pm = -INFINITY;
    #pragma unroll
    for (int mi=0; mi<4; ++mi) {
      #pragma unroll
      for (int r=0; r<4; ++r) {
        unsigned u = bias_lds[w*1040 + lr*65 + (mi*16 + kg*4 + r)];
        float b = h2f((unsigned short)((h&1) ? (u>>16) : (u & 0xffff)));
        s[mi][r] += b;
        pm = fmaxf(pm, s[mi][r]);
      }
    }
    pm = fmaxf(pm, __shfl_xor(pm, 16));
    pm = fmaxf(pm, __shfl_xor(pm, 32));
    m[hh] = pm;
    float ev[4][4];
    float ts = 0.f;
    #pragma unroll
    for (int mi=0; mi<4; ++mi)
      #pragma unroll
      for (int r=0; r<4; ++r) { float e_ = __expf(s[mi][r] - pm); ev[mi][r] = e_; ts += e_; }
    ts += __shfl_xor(ts, 16);
    ts += __shfl_xor(ts, 32);
    lsum[hh] = ts;
    accO[hh][0] = (f32x4){0,0,0,0};
    accO[hh][1] = (f32x4){0,0,0,0};
    unsigned u01[4][2];
    #pragma unroll
    for (int mi=0; mi<4; ++mi) {
      #pragma unroll
      for (int pr=0; pr<2; ++pr) {
        unsigned lo = (unsigned)(unsigned short)f2bf(ev[mi][2*pr]);
        unsigned hi = (unsigned)(unsigned short)f2bf(ev[mi][2*pr+1]);
        u01[mi][pr] = (hi<<16) | lo;
      }
    }
    #pragma unroll
    for (int ks=0; ks<2; ++ks) {
      unsigned Wd[4];
      #pragma unroll
      for (int wd=0; wd<4; ++wd) {
        int srcLane = lr + ((2*(kg&1) + (wd>>1)) << 4);
        int a = __shfl((int)u01[2*ks][wd&1],   srcLane);
        int b = __shfl((int)u01[2*ks+1][wd&1], srcLane);
        Wd[wd] = (kg>>1) ? (unsigned)b : (unsigned)a;
      }
      union { unsigned u[4]; bf16x8 v; } cvt;
      cvt.u[0]=Wd[0]; cvt.u[1]=Wd[1]; cvt.u[2]=Wd[2]; cvt.u[3]=Wd[3];
      bf16x8 pfrag = cvt.v;
      #pragma unroll
      for (int mi=0; mi<2; ++mi) {
        bf16x8 vf = *(const bf16x8*)(Vt + (size_t)(h*DH + mi*16 + lr)*N + j0 + ks*32 + kg*8);
        accO[hh][mi] = __builtin_amdgcn_mfma_f32_16x16x32_bf16(vf, pfrag, accO[hh][mi], 0, 0, 0);
      }
    }
  }
  // ---- write partials (Po in bf16) ----
  #pragma unroll
  for (int hh=0; hh<2; ++hh) {
    int h = w*2 + hh;
    if (kg == 0) {
      Pm[(size_t)(jc*16+h)*N + i0 + lr] = m[hh];
      Pl[(size_t)(jc*16+h)*N + i0 + lr] = lsum[hh];
    }
    #pragma unroll
    for (int mi=0; mi<2; ++mi)
      #pragma unroll
      for (int r=0; r<4; ++r) {
        int d = mi*16 + kg*4 + r;
        Po[((size_t)(jc*16+h)*DH + d)*N + i0 + lr] = f2bf(accO[hh][mi][r]);
      }
  }
}

// ---------------- combine partials -> ob (bf16 [i][h*32+d]) ------------------
__global__ void attn_combine(const float* __restrict__ Pm, const float* __restrict__ Pl,
                             const short* __restrict__ Po, short* __restrict__ ob) {
  int h = blockIdx.y;
  int i = blockIdx.x*64 + (threadIdx.x & 63);
  int dq = threadIdx.x >> 6;                 // 0..3 (8 d's each)
  float mcs[16];
  float M = -INFINITY;
  #pragma unroll
  for (int c=0; c<16; ++c) { mcs[c] = Pm[(size_t)(c*16+h)*N + i]; M = fmaxf(M, mcs[c]); }
  float wc[16]; float L = 0.f;
  #pragma unroll
  for (int c=0; c<16; ++c) { wc[c] = __expf(mcs[c]-M); L += Pl[(size_t)(c*16+h)*N + i]*wc[c]; }
  float invL = 1.f / L;
  float o[8] = {0,0,0,0,0,0,0,0};
  #pragma unroll
  for (int c=0; c<16; ++c) {
    #pragma unroll
    for (int dd=0; dd<8; ++dd)
      o[dd] += wc[c] * bf2fu((unsigned short)Po[((size_t)(c*16+h)*DH + dq*8+dd)*N + i]);
  }
  short4v s0 = { f2bf(o[0]*invL), f2bf(o[1]*invL), f2bf(o[2]*invL), f2bf(o[3]*invL) };
  short4v s1 = { f2bf(o[4]*invL), f2bf(o[5]*invL), f2bf(o[6]*invL), f2bf(o[7]*invL) };
  *(short4v*)(ob + (size_t)i*HID + h*DH + dq*8) = s0;
  *(short4v*)(ob + (size_t)i*HID + h*DH + dq*8 + 4) = s1;
}

// ---------------- residual + layernorm (+ optional bf16 copy) ----------------
__global__ void add_ln_k(const float* __restrict__ a, const float* __restrict__ b,
                         const float* __restrict__ g, const float* __restrict__ be,
                         float* __restrict__ out, short* __restrict__ outb) {
  int i = blockIdx.x; int tid = threadIdx.x;
  float4 av = ((const float4*)(a + (size_t)i*HID))[tid];
  float4 bv = ((const float4*)(b + (size_t)i*HID))[tid];
  float4 v;
  v.x = av.x+bv.x; v.y = av.y+bv.y; v.z = av.z+bv.z; v.w = av.w+bv.w;
  float s = v.x+v.y+v.z+v.w;
  float s2 = v.x*v.x+v.y*v.y+v.z*v.z+v.w*v.w;
  for (int o = 32; o; o >>= 1) { s += __shfl_xor(s, o); s2 += __shfl_xor(s2, o); }
  __shared__ float sa[2], sb[2];
  if ((tid & 63) == 0) { sa[tid>>6] = s; sb[tid>>6] = s2; }
  __syncthreads();
  s = sa[0]+sa[1]; s2 = sb[0]+sb[1];
  float mean = s*(1.f/HID);
  float var = s2*(1.f/HID) - mean*mean;
  float rinv = rsqrtf(var + 1e-5f);
  float4 gv = ((const float4*)g)[tid];
  float4 bev = ((const float4*)be)[tid];
  float4 r;
  r.x = (v.x-mean)*rinv*gv.x + bev.x;
  r.y = (v.y-mean)*rinv*gv.y + bev.y;
  r.z = (v.z-mean)*rinv*gv.z + bev.z;
  r.w = (v.w-mean)*rinv*gv.w + bev.w;
  ((float4*)(out + (size_t)i*HID))[tid] = r;
  if (outb) {
    short4v o = { f2bf(r.x), f2bf(r.y), f2bf(r.z), f2bf(r.w) };
    ((short4v*)(outb + (size_t)i*HID))[tid] = o;
  }
}

extern "C" void kernel_launch(void* const* d_in, const int* in_sizes, int n_in,
                              void* d_out, int out_size, void* d_ws, size_t ws_size,
                              hipStream_t stream) {
  const float* x            = (const float*)d_in[0];
  const int*   spatial_pos  = (const int*)d_in[1];
  const int*   edge_input   = (const int*)d_in[2];
  const int*   in_degree    = (const int*)d_in[3];
  const int*   out_degree   = (const int*)d_in[4];
  const float* spatial_emb  = (const float*)d_in[5];
  const float* edge_emb     = (const float*)d_in[6];
  const float* edge_pos_emb = (const float*)d_in[7];
  const float* in_deg_emb   = (const float*)d_in[8];
  const float* out_deg_emb  = (const float*)d_in[9];
  const float* Wq = (const float*)d_in[10]; const float* bq = (const float*)d_in[11];
  const float* Wk = (const float*)d_in[12]; const float* bk = (const float*)d_in[13];
  const float* Wv = (const float*)d_in[14]; const float* bv = (const float*)d_in[15];
  const float* Wo = (const float*)d_in[16]; const float* bo = (const float*)d_in[17];
  const float* W1 = (const float*)d_in[18]; const float* b1 = (const float*)d_in[19];
  const float* W2 = (const float*)d_in[20]; const float* b2 = (const float*)d_in[21];
  const float* g1 = (const float*)d_in[22]; const float* be1 = (const float*)d_in[23];
  const float* g2 = (const float*)d_in[24]; const float* be2 = (const float*)d_in[25];

  char* W = (char*)d_ws;
  unsigned char* Tb8  = (unsigned char*)(W + 0);        // 65,600 B
  unsigned char* seb8 = (unsigned char*)(W + 131072);   // 8,192 B
  float* h    = (float*)(W + 262144);       // 2 MB
  float* y    = (float*)(W + 2359296);      // 2 MB
  float* h1   = (float*)(W + 4456448);      // 2 MB
  short* hb   = (short*)(W + 6553600);      // 1 MB
  short* qb   = (short*)(W + 7602176);      // 1 MB
  short* kb   = (short*)(W + 8650752);      // 1 MB
  short* Vt   = (short*)(W + 9699328);      // 1 MB
  short* ob   = (short*)(W + 10747904);     // 1 MB
  short* h1b  = (short*)(W + 11796480);     // 1 MB
  short* midb = (short*)(W + 12845056);     // 2 MB
  float* f2   = (float*)(W + 14942208);     // 2 MB
  short* Wtq  = (short*)(W + 17039360);     // 512 KB
  short* Wtk  = (short*)(W + 17563648);
  short* Wtv  = (short*)(W + 18087936);
  short* Wto  = (short*)(W + 18612224);
  short* Wt1  = (short*)(W + 19136512);     // 1 MB
  short* Wt2  = (short*)(W + 20185088);     // 1 MB
  float* Pm   = (float*)(W + 21233664);     // 1 MB
  float* Pl   = (float*)(W + 22282240);     // 1 MB
  short* Po   = (short*)(W + 23330816);     // 16 MB (bf16)
  unsigned* Bias = (unsigned*)(W + 40108032); // 32 MB -> ends 73,662,464
  float* out  = (float*)d_out;

  centrality_k<<<N, 128, 0, stream>>>(x, in_degree, out_degree, in_deg_emb, out_deg_emb, h, hb);
  prep_tables<<<257, 256, 0, stream>>>(edge_emb, edge_pos_emb, spatial_emb, Tb8, seb8);

  bias_gather<<<4096, 256, 0, stream>>>(spatial_pos, edge_input, seb8, Tb8, Bias);

  wtr4_k<<<dim3(16,16,4), 256, 0, stream>>>(Wq, Wk, Wv, Wo, Wtq, Wtk, Wtv, Wto);
  wtr_k<<<dim3(32,16), 256, 0, stream>>>(W1, Wt1, 512, 1024);
  wtr_k<<<dim3(16,32), 256, 0, stream>>>(W2, Wt2, 1024, 512);

  qkv_gemm<<<dim3(16,16,3), 256, 0, stream>>>(hb, Wtq, Wtk, Wtv, bq, bk, bv, qb, kb, Vt);

  fused_attn<<<dim3(16,64), 512, 0, stream>>>(qb, kb, Vt, Bias, Pm, Pl, Po);
  attn_combine<<<dim3(16,16), 256, 0, stream>>>(Pm, Pl, Po, ob);

  gemm_mfma<32,0,0><<<dim3(16,16), 256, 0, stream>>>(ob, Wto, bo, 1.f, y, nullptr, 512, 512);
  add_ln_k<<<N, 128, 0, stream>>>(h, y, g1, be1, h1, h1b);
  gemm_mfma<64,1,1><<<dim3(16,16), 256, 0, stream>>>(h1b, Wt1, b1, 1.f, nullptr, midb, 512, 1024);
  gemm_mfma<32,0,0><<<dim3(16,16), 256, 0, stream>>>(midb, Wt2, b2, 1.f, f2, nullptr, 1024, 512);
  add_ln_k<<<N, 128, 0, stream>>>(h1, f2, g2, be2, out, nullptr);
}